// Round 4
// baseline (501.877 us; speedup 1.0000x reference)
//
#include <hip/hip_runtime.h>
#include <stdint.h>

// irreps linear: 128x0e+128x1o+128x2e, per-block y[z,w,i] = a * sum_u W[u,w] x[z,u,i]
// GEMMs with M=(i,z), N=w(128), K=u(128). bf16 MFMA, f32 accum.
// Persistent WGs (768 = 3/CU), W in registers, double-buffered LDS x with
// register prefetch (T14). D=3/5 outputs transposed through dead LDS and
// stored as coalesced f32x4. D=5 stages in TWO half-tiles through bc only
// (fixes round-3 race: out-stage must never overlap bn).

#define NROWS 100000
#define ROWLEN 1152

typedef __attribute__((ext_vector_type(8))) short bf16x8;
typedef __attribute__((ext_vector_type(4))) float f32x4;
typedef __attribute__((ext_vector_type(4))) ushort u16x4;

__device__ __forceinline__ ushort f2b(float f) {
  union { float f; uint32_t u; } v; v.f = f;
  uint32_t r = v.u + 0x7FFFu + ((v.u >> 16) & 1u);  // RNE; inputs finite
  return (ushort)(r >> 16);
}

// ---- x staging helpers ---------------------------------------------------
template<int D, int TM, bool G>
__device__ __forceinline__ void load_tile(const float* __restrict__ xb, int t,
                                          int tid, f32x4 (&vf)[TM / 8][D])
{
  #pragma unroll
  for (int p = 0; p < TM / 8; ++p) {
    int ch = p * 256 + tid;
    int zl = ch >> 5, cc = ch & 31;
    int z  = t * TM + zl;
    const float* src = xb + (size_t)z * ROWLEN + cc * 4 * D;
    #pragma unroll
    for (int j = 0; j < D; ++j) {
      f32x4 v = {0.f, 0.f, 0.f, 0.f};
      if (!G || z < NROWS) v = *(const f32x4*)(src + 4 * j);
      vf[p][j] = v;
    }
  }
}

// LDS A layout: [m][u] bf16, row = 256 B, 16B-chunk XOR swizzle chunk^=(m&7).
template<int D, int TM>
__device__ __forceinline__ void write_tile(char* __restrict__ buf, int tid,
                                           f32x4 (&vf)[TM / 8][D])
{
  #pragma unroll
  for (int p = 0; p < TM / 8; ++p) {
    int ch = p * 256 + tid;
    int zl = ch >> 5, cc = ch & 31;
    #pragma unroll
    for (int i = 0; i < D; ++i) {
      int m = i * TM + zl;
      u16x4 pk;
      #pragma unroll
      for (int u = 0; u < 4; ++u) {
        int e = i + D * u;            // compile-time after unroll
        pk[u] = f2b(vf[p][e >> 2][e & 3]);
      }
      int byte = m * 256 + ((((cc >> 1) ^ (m & 7)) << 4) | ((cc & 1) << 3));
      *(u16x4*)(buf + byte) = pk;
    }
  }
}

// ---- direct store (D=1 only) ---------------------------------------------
template<bool G, int D, int TM, int MTILES>
__device__ __forceinline__ void store_direct(float* __restrict__ ob, int z0,
                                             int lane, int nbase,
                                             f32x4 (&acc)[MTILES][2])
{
  const int rbase = ((lane >> 4) & 3) << 2;
  #pragma unroll
  for (int mt = 0; mt < MTILES; ++mt) {
    #pragma unroll
    for (int r = 0; r < 4; ++r) {
      int m  = mt * 16 + rbase + r;
      int i  = m / TM, zl = m % TM;
      int z  = z0 + zl;
      if (G && z >= NROWS) continue;
      float* orow = ob + (size_t)z * ROWLEN + i;
      orow[(size_t)nbase * D]        = acc[mt][0][r];
      orow[(size_t)(nbase + 16) * D] = acc[mt][1][r];
    }
  }
}

// ---- D=3: full out tile [16][384] f32 in spare(rows 0..9) + bc(rows 10..15)
__device__ __forceinline__ char* row_base3(char* lds, char* bcp, int zl) {
  return (zl < 10) ? (lds + 24576 + zl * 1536) : (bcp + (zl - 10) * 1536);
}

template<int MTILES>
__device__ __forceinline__ void stage_out3(char* lds, char* bcp, int lane,
                                           int nbase, f32x4 (&acc)[MTILES][2])
{
  const int rbase = ((lane >> 4) & 3) << 2;
  #pragma unroll
  for (int mt = 0; mt < MTILES; ++mt) {
    #pragma unroll
    for (int nt = 0; nt < 2; ++nt) {
      const int col = (nbase + nt * 16) * 3 + mt;   // i == mt (TM==16)
      #pragma unroll
      for (int r = 0; r < 4; ++r) {
        const int zl = rbase + r;
        char* base = row_base3(lds, bcp, zl);
        int byte = ((((col >> 2) ^ (zl & 7)) << 4) | ((col & 3) << 2));
        *(float*)(base + byte) = acc[mt][nt][r];
      }
    }
  }
}

__device__ __forceinline__ void store_out3(char* lds, char* bcp,
                                           float* __restrict__ ob, int z0,
                                           int tid)
{
  #pragma unroll
  for (int p = 0; p < 6; ++p) {          // 16 rows * 96 chunks / 256 threads
    int e   = p * 256 + tid;
    int zl  = e / 96;
    int c16 = e - zl * 96;
    char* base = row_base3(lds, bcp, zl);
    f32x4 v = *(const f32x4*)(base + ((c16 ^ (zl & 7)) << 4));
    *(f32x4*)(ob + (size_t)(z0 + zl) * ROWLEN + c16 * 4) = v;
  }
}

// ---- D=5: half out tile (8 rows x 2560B = 20480B) staged through bc only --
template<int H, int MTILES>
__device__ __forceinline__ void stage_half5(char* bc, int lane, int nbase,
                                            f32x4 (&acc)[MTILES][2])
{
  const int rbase = ((lane >> 4) & 3) << 2;
  if ((rbase >> 3) != H) return;         // whole quarter-wave participates or not
  #pragma unroll
  for (int mt = 0; mt < MTILES; ++mt) {
    #pragma unroll
    for (int nt = 0; nt < 2; ++nt) {
      const int col = (nbase + nt * 16) * 5 + mt;   // i == mt (TM==16)
      #pragma unroll
      for (int r = 0; r < 4; ++r) {
        const int zr = (rbase + r) & 7;
        int byte = zr * 2560 + ((((col >> 2) ^ zr) << 4) | ((col & 3) << 2));
        *(float*)(bc + byte) = acc[mt][nt][r];
      }
    }
  }
}

template<int H>
__device__ __forceinline__ void store_half5(char* bc, float* __restrict__ ob,
                                            int z0, int tid)
{
  #pragma unroll
  for (int p = 0; p < 5; ++p) {          // 8 rows * 160 chunks / 256 threads
    int e   = p * 256 + tid;
    int zr  = e / 160;
    int c16 = e - zr * 160;
    f32x4 v = *(const f32x4*)(bc + zr * 2560 + ((c16 ^ zr) << 4));
    *(f32x4*)(ob + (size_t)(z0 + H * 8 + zr) * ROWLEN + c16 * 4) = v;
  }
}

// ---- persistent per-irrep path ------------------------------------------
// STAGE: 0 = direct store, 1 = D=3 spare+bc staging, 2 = D=5 half-tile staging
template<int D, int TM, bool GUARD, int STAGE, int NWGS>
__device__ __forceinline__ void linpath(const float* __restrict__ xb,
                                        const float* __restrict__ wb,
                                        float* __restrict__ ob,
                                        int wgid, char* lds)
{
  constexpr int MT     = TM * D;
  constexpr int MTILES = MT / 16;
  constexpr int PT     = TM / 8;
  constexpr int NTILES = (NROWS + TM - 1) / TM;
  constexpr int BUFB   = MT * 256;
  constexpr float ALPHA = 0.088388347648318447f;  // 128^-0.5

  const int tid   = threadIdx.x;
  const int lane  = tid & 63;
  const int wv    = tid >> 6;
  const int l15   = lane & 15;
  const int kr    = ((lane >> 4) & 3) << 3;
  const int nbase = (wv << 5) + l15;

  // weights -> registers once (K=128 x N=32 per wave), ALPHA folded
  bf16x8 bfr[2][4];
  #pragma unroll
  for (int nt = 0; nt < 2; ++nt)
    #pragma unroll
    for (int ks = 0; ks < 4; ++ks)
      #pragma unroll
      for (int j = 0; j < 8; ++j)
        bfr[nt][ks][j] =
            (short)f2b(wb[(ks * 32 + kr + j) * 128 + nbase + nt * 16] * ALPHA);

  char* buf0 = lds;
  char* buf1 = lds + BUFB;

  // prologue: stage first tile
  int t0 = wgid;
  {
    f32x4 vf[PT][D];
    if (GUARD && t0 == NTILES - 1) load_tile<D, TM, true>(xb, t0, tid, vf);
    else                           load_tile<D, TM, false>(xb, t0, tid, vf);
    write_tile<D, TM>(buf0, tid, vf);
  }
  __syncthreads();

  int cur = 0;
  for (int t = t0; t < NTILES; t += NWGS) {
    char* bc = cur ? buf1 : buf0;
    char* bn = cur ? buf0 : buf1;
    const int tn = t + NWGS;
    const bool have = tn < NTILES;

    // 1. issue next tile's global loads into regs (hide under MFMA)
    f32x4 vf[PT][D];
    if (have) {
      if (GUARD && tn == NTILES - 1) load_tile<D, TM, true>(xb, tn, tid, vf);
      else                           load_tile<D, TM, false>(xb, tn, tid, vf);
    }

    // 2. MFMA on current buffer
    f32x4 acc[MTILES][2];
    #pragma unroll
    for (int mt = 0; mt < MTILES; ++mt) {
      acc[mt][0] = f32x4{0.f, 0.f, 0.f, 0.f};
      acc[mt][1] = f32x4{0.f, 0.f, 0.f, 0.f};
    }
    #pragma unroll
    for (int ks = 0; ks < 4; ++ks) {
      const int chunkbase = ks * 4 + ((lane >> 4) & 3);
      #pragma unroll
      for (int mt = 0; mt < MTILES; ++mt) {
        int m = (mt << 4) + l15;
        int byte = m * 256 + ((chunkbase ^ (m & 7)) << 4);
        bf16x8 a = *(const bf16x8*)(bc + byte);
        acc[mt][0] = __builtin_amdgcn_mfma_f32_16x16x32_bf16(a, bfr[0][ks], acc[mt][0], 0, 0, 0);
        acc[mt][1] = __builtin_amdgcn_mfma_f32_16x16x32_bf16(a, bfr[1][ks], acc[mt][1], 0, 0, 0);
      }
    }

    if (STAGE == 1) {
      // out tile -> spare + dead bc (disjoint from bn), coalesced store
      __syncthreads();                       // all waves done reading bc
      stage_out3<MTILES>(lds, bc, lane, nbase, acc);
      if (have) write_tile<D, TM>(bn, tid, vf);
      __syncthreads();                       // staging + next-x visible
      store_out3(lds, bc, ob, t * TM, tid);
      // next iter's post-MFMA barrier orders these reads before reuse
    } else if (STAGE == 2) {
      // two half-tiles through dead bc only (never touches bn)
      __syncthreads();                       // all waves done reading bc
      stage_half5<0, MTILES>(bc, lane, nbase, acc);
      if (have) write_tile<D, TM>(bn, tid, vf);
      __syncthreads();                       // half0 staged, next-x visible
      store_half5<0>(bc, ob, t * TM, tid);
      __syncthreads();                       // half0 reads done
      stage_half5<1, MTILES>(bc, lane, nbase, acc);
      __syncthreads();                       // half1 staged
      store_half5<1>(bc, ob, t * TM, tid);
      // next iter's post-MFMA barrier orders these reads before reuse
    } else {
      if (have) write_tile<D, TM>(bn, tid, vf);
      if (GUARD && t == NTILES - 1)
        store_direct<true, D, TM, MTILES>(ob, t * TM, lane, nbase, acc);
      else
        store_direct<false, D, TM, MTILES>(ob, t * TM, lane, nbase, acc);
      __syncthreads();
    }
    cur ^= 1;
  }
}

// WG split ~ proportional to bytes (1:3:5)
constexpr int NW1 = 84;    // D=1, TM=64, 1563 tiles
constexpr int NW3 = 254;   // D=3, TM=16, 6250 tiles
constexpr int NW5 = 430;   // D=5, TM=16, 6250 tiles

__global__ __launch_bounds__(256, 3)
void linear_irreps_kernel(const float* __restrict__ x, const float* __restrict__ w,
                          float* __restrict__ out)
{
  extern __shared__ __align__(16) char lds[];
  int wg = blockIdx.x;
  if (wg < NW1) {
    linpath<1, 64, true,  0, NW1>(x,       w,         out,       wg,             lds);
  } else if (wg < NW1 + NW3) {
    linpath<3, 16, false, 1, NW3>(x + 128, w + 16384, out + 128, wg - NW1,       lds);
  } else {
    linpath<5, 16, false, 2, NW5>(x + 512, w + 32768, out + 512, wg - NW1 - NW3, lds);
  }
}

extern "C" void kernel_launch(void* const* d_in, const int* in_sizes, int n_in,
                              void* d_out, int out_size, void* d_ws, size_t ws_size,
                              hipStream_t stream) {
  const float* x = (const float*)d_in[0];
  const float* w = (const float*)d_in[1];
  float* out = (float*)d_out;
  (void)in_sizes; (void)n_in; (void)out_size; (void)d_ws; (void)ws_size;
  dim3 grid(NW1 + NW3 + NW5);
  dim3 block(256);
  hipLaunchKernelGGL(linear_irreps_kernel, grid, block, 40960, stream, x, w, out);
}

// Round 5
// 204.448 us; speedup vs baseline: 2.4548x; 2.4548x over previous
//
#include <hip/hip_runtime.h>
#include <stdint.h>

// irreps linear: 128x0e+128x1o+128x2e, per-block y[z,w,i] = a * sum_u W[u,w] x[z,u,i]
// GEMMs with M=(i,z), N=w(128), K=u(128). bf16 MFMA, f32 accum.
// Round-2 structure (persistent WGs, W in registers, double-buffered LDS x,
// register prefetch T14, direct stores, ONE barrier/tile) + occupancy bump:
// grid 1024 = 4 WGs/CU (LDS 4x40960 = 160KiB exactly), launch_bounds(256,4).
// Round-4 lesson: extra barriers per tile drain vmcnt and kill the pipeline.

#define NROWS 100000
#define ROWLEN 1152

typedef __attribute__((ext_vector_type(8))) short bf16x8;
typedef __attribute__((ext_vector_type(4))) float f32x4;
typedef __attribute__((ext_vector_type(4))) ushort u16x4;

__device__ __forceinline__ ushort f2b(float f) {
  union { float f; uint32_t u; } v; v.f = f;
  uint32_t r = v.u + 0x7FFFu + ((v.u >> 16) & 1u);  // RNE; inputs finite
  return (ushort)(r >> 16);
}

// ---- staging helpers ----------------------------------------------------
// Chunk = 4 consecutive u x D i's = 4D consecutive floats of x's natural row.
// 32 chunks per row; thread handles TM/8 chunks per tile.

template<int D, int TM, bool G>
__device__ __forceinline__ void load_tile(const float* __restrict__ xb, int t,
                                          int tid, f32x4 (&vf)[TM / 8][D])
{
  #pragma unroll
  for (int p = 0; p < TM / 8; ++p) {
    int ch = p * 256 + tid;
    int zl = ch >> 5, cc = ch & 31;
    int z  = t * TM + zl;
    const float* src = xb + (size_t)z * ROWLEN + cc * 4 * D;
    #pragma unroll
    for (int j = 0; j < D; ++j) {
      f32x4 v = {0.f, 0.f, 0.f, 0.f};
      if (!G || z < NROWS) v = *(const f32x4*)(src + 4 * j);
      vf[p][j] = v;
    }
  }
}

// LDS A layout: [m][u] bf16, row = 256 B, 16B-chunk XOR swizzle chunk^=(m&7).
template<int D, int TM>
__device__ __forceinline__ void write_tile(char* __restrict__ buf, int tid,
                                           f32x4 (&vf)[TM / 8][D])
{
  #pragma unroll
  for (int p = 0; p < TM / 8; ++p) {
    int ch = p * 256 + tid;
    int zl = ch >> 5, cc = ch & 31;
    #pragma unroll
    for (int i = 0; i < D; ++i) {
      int m = i * TM + zl;
      u16x4 pk;
      #pragma unroll
      for (int u = 0; u < 4; ++u) {
        int e = i + D * u;            // compile-time after unroll
        pk[u] = f2b(vf[p][e >> 2][e & 3]);
      }
      int byte = m * 256 + ((((cc >> 1) ^ (m & 7)) << 4) | ((cc & 1) << 3));
      *(u16x4*)(buf + byte) = pk;
    }
  }
}

template<bool G, int D, int TM, int MTILES>
__device__ __forceinline__ void store_tile(float* __restrict__ ob, int z0,
                                           int lane, int nbase,
                                           f32x4 (&acc)[MTILES][2])
{
  const int rbase = ((lane >> 4) & 3) << 2;
  #pragma unroll
  for (int mt = 0; mt < MTILES; ++mt) {
    #pragma unroll
    for (int r = 0; r < 4; ++r) {
      int m  = mt * 16 + rbase + r;
      int i  = m / TM, zl = m % TM;
      int z  = z0 + zl;
      if (G && z >= NROWS) continue;
      float* orow = ob + (size_t)z * ROWLEN + i;
      orow[(size_t)nbase * D]        = acc[mt][0][r];
      orow[(size_t)(nbase + 16) * D] = acc[mt][1][r];
    }
  }
}

// ---- persistent per-irrep path ------------------------------------------
template<int D, int TM, bool GUARD, int NWGS>
__device__ __forceinline__ void linpath(const float* __restrict__ xb,
                                        const float* __restrict__ wb,
                                        float* __restrict__ ob,
                                        int wgid, char* lds)
{
  constexpr int MT     = TM * D;
  constexpr int MTILES = MT / 16;
  constexpr int PT     = TM / 8;
  constexpr int NTILES = (NROWS + TM - 1) / TM;
  constexpr int BUFB   = MT * 256;
  constexpr float ALPHA = 0.088388347648318447f;  // 128^-0.5

  const int tid   = threadIdx.x;
  const int lane  = tid & 63;
  const int wv    = tid >> 6;
  const int l15   = lane & 15;
  const int kr    = ((lane >> 4) & 3) << 3;
  const int nbase = (wv << 5) + l15;

  // ---- weights -> registers once per WG (K=128 x N=32 per wave), ALPHA folded
  bf16x8 bfr[2][4];
  #pragma unroll
  for (int nt = 0; nt < 2; ++nt)
    #pragma unroll
    for (int ks = 0; ks < 4; ++ks)
      #pragma unroll
      for (int j = 0; j < 8; ++j)
        bfr[nt][ks][j] =
            (short)f2b(wb[(ks * 32 + kr + j) * 128 + nbase + nt * 16] * ALPHA);

  char* buf0 = lds;
  char* buf1 = lds + BUFB;

  // ---- prologue: stage first tile ----
  int t0 = wgid;
  {
    f32x4 vf[PT][D];
    if (GUARD && t0 == NTILES - 1) load_tile<D, TM, true>(xb, t0, tid, vf);
    else                           load_tile<D, TM, false>(xb, t0, tid, vf);
    write_tile<D, TM>(buf0, tid, vf);
  }
  __syncthreads();

  int cur = 0;
  for (int t = t0; t < NTILES; t += NWGS) {
    char* bc = cur ? buf1 : buf0;
    char* bn = cur ? buf0 : buf1;
    const int tn = t + NWGS;
    const bool have = tn < NTILES;

    // 1. issue next tile's global loads into regs (latency hides under MFMA)
    f32x4 vf[PT][D];
    if (have) {
      if (GUARD && tn == NTILES - 1) load_tile<D, TM, true>(xb, tn, tid, vf);
      else                           load_tile<D, TM, false>(xb, tn, tid, vf);
    }

    // 2. MFMA on current buffer
    f32x4 acc[MTILES][2];
    #pragma unroll
    for (int mt = 0; mt < MTILES; ++mt) {
      acc[mt][0] = f32x4{0.f, 0.f, 0.f, 0.f};
      acc[mt][1] = f32x4{0.f, 0.f, 0.f, 0.f};
    }
    #pragma unroll
    for (int ks = 0; ks < 4; ++ks) {
      const int chunkbase = ks * 4 + ((lane >> 4) & 3);  // (ks*32+kr)>>3
      #pragma unroll
      for (int mt = 0; mt < MTILES; ++mt) {
        int m = (mt << 4) + l15;
        int byte = m * 256 + ((chunkbase ^ (m & 7)) << 4);
        bf16x8 a = *(const bf16x8*)(bc + byte);
        acc[mt][0] = __builtin_amdgcn_mfma_f32_16x16x32_bf16(a, bfr[0][ks], acc[mt][0], 0, 0, 0);
        acc[mt][1] = __builtin_amdgcn_mfma_f32_16x16x32_bf16(a, bfr[1][ks], acc[mt][1], 0, 0, 0);
      }
    }

    // 3. convert + LDS-write next tile (global loads have landed by now)
    if (have) write_tile<D, TM>(bn, tid, vf);

    // 4. store current tile's output
    if (GUARD && t == NTILES - 1)
      store_tile<true, D, TM, MTILES>(ob, t * TM, lane, nbase, acc);
    else
      store_tile<false, D, TM, MTILES>(ob, t * TM, lane, nbase, acc);

    __syncthreads();
    cur ^= 1;
  }
}

// WG split proportional to bytes (1:3:5), grid = 1024 = 4 WGs/CU.
// Per-WG traffic: D1 13.7 tiles*65KB = 0.89MB, D3 18.3*48KB = 0.88MB,
// D5 11.0*80KB = 0.88MB -> balanced.
constexpr int NW1 = 114;   // D=1, TM=64, 1563 tiles
constexpr int NW3 = 341;   // D=3, TM=16, 6250 tiles
constexpr int NW5 = 569;   // D=5, TM=16, 6250 tiles

__global__ __launch_bounds__(256, 4)
void linear_irreps_kernel(const float* __restrict__ x, const float* __restrict__ w,
                          float* __restrict__ out)
{
  extern __shared__ __align__(16) char lds[];
  int wg = blockIdx.x;
  if (wg < NW1) {
    linpath<1, 64, true,  NW1>(x,       w,         out,       wg,             lds);
  } else if (wg < NW1 + NW3) {
    linpath<3, 16, false, NW3>(x + 128, w + 16384, out + 128, wg - NW1,       lds);
  } else {
    linpath<5, 16, false, NW5>(x + 512, w + 32768, out + 512, wg - NW1 - NW3, lds);
  }
}

extern "C" void kernel_launch(void* const* d_in, const int* in_sizes, int n_in,
                              void* d_out, int out_size, void* d_ws, size_t ws_size,
                              hipStream_t stream) {
  const float* x = (const float*)d_in[0];
  const float* w = (const float*)d_in[1];
  float* out = (float*)d_out;
  (void)in_sizes; (void)n_in; (void)out_size; (void)d_ws; (void)ws_size;
  dim3 grid(NW1 + NW3 + NW5);
  dim3 block(256);
  hipLaunchKernelGGL(linear_irreps_kernel, grid, block, 40960, stream, x, w, out);
}

// Round 6
// 201.440 us; speedup vs baseline: 2.4915x; 1.0149x over previous
//
#include <hip/hip_runtime.h>
#include <stdint.h>

// irreps linear: 128x0e+128x1o+128x2e, per-block y[z,w,i] = a * sum_u W[u,w] x[z,u,i]
// GEMMs with M=(i,z), N=w(128), K=u(128). bf16 MFMA, f32 accum.
// Persistent WGs (1024 = 4/CU), W in registers, double-buffered LDS x,
// register prefetch (T14), ONE barrier/tile. NEW (r6): dense per-lane stores —
// for TM=16 paths lane holds all D consecutive out cols (i==mt), so store
// dwordx4+dword (D=5) / dwordx2+dword (D=3) instead of D scattered dwords.

#define NROWS 100000
#define ROWLEN 1152

typedef __attribute__((ext_vector_type(8))) short bf16x8;
typedef __attribute__((ext_vector_type(4))) float f32x4;
typedef __attribute__((ext_vector_type(4))) ushort u16x4;
typedef float f32x4u __attribute__((ext_vector_type(4), aligned(4)));
typedef float f32x2u __attribute__((ext_vector_type(2), aligned(4)));

__device__ __forceinline__ ushort f2b(float f) {
  union { float f; uint32_t u; } v; v.f = f;
  uint32_t r = v.u + 0x7FFFu + ((v.u >> 16) & 1u);  // RNE; inputs finite
  return (ushort)(r >> 16);
}

// ---- staging helpers ----------------------------------------------------
template<int D, int TM, bool G>
__device__ __forceinline__ void load_tile(const float* __restrict__ xb, int t,
                                          int tid, f32x4 (&vf)[TM / 8][D])
{
  #pragma unroll
  for (int p = 0; p < TM / 8; ++p) {
    int ch = p * 256 + tid;
    int zl = ch >> 5, cc = ch & 31;
    int z  = t * TM + zl;
    const float* src = xb + (size_t)z * ROWLEN + cc * 4 * D;
    #pragma unroll
    for (int j = 0; j < D; ++j) {
      f32x4 v = {0.f, 0.f, 0.f, 0.f};
      if (!G || z < NROWS) v = *(const f32x4*)(src + 4 * j);
      vf[p][j] = v;
    }
  }
}

// LDS A layout: [m][u] bf16, row = 256 B, 16B-chunk XOR swizzle chunk^=(m&7).
template<int D, int TM>
__device__ __forceinline__ void write_tile(char* __restrict__ buf, int tid,
                                           f32x4 (&vf)[TM / 8][D])
{
  #pragma unroll
  for (int p = 0; p < TM / 8; ++p) {
    int ch = p * 256 + tid;
    int zl = ch >> 5, cc = ch & 31;
    #pragma unroll
    for (int i = 0; i < D; ++i) {
      int m = i * TM + zl;
      u16x4 pk;
      #pragma unroll
      for (int u = 0; u < 4; ++u) {
        int e = i + D * u;            // compile-time after unroll
        pk[u] = f2b(vf[p][e >> 2][e & 3]);
      }
      int byte = m * 256 + ((((cc >> 1) ^ (m & 7)) << 4) | ((cc & 1) << 3));
      *(u16x4*)(buf + byte) = pk;
    }
  }
}

// ---- stores --------------------------------------------------------------
// D=1 (TM=64): col = nbase, rows dense across lanes -> scalar dwords are dense.
template<bool G, int TM, int MTILES>
__device__ __forceinline__ void store_d1(float* __restrict__ ob, int z0,
                                         int lane, int nbase,
                                         f32x4 (&acc)[MTILES][2])
{
  const int rbase = ((lane >> 4) & 3) << 2;
  #pragma unroll
  for (int mt = 0; mt < MTILES; ++mt) {
    #pragma unroll
    for (int r = 0; r < 4; ++r) {
      int zl = mt * 16 + rbase + r;
      int z  = z0 + zl;
      if (G && z >= NROWS) continue;
      float* orow = ob + (size_t)z * ROWLEN;
      orow[nbase]      = acc[mt][0][r];
      orow[nbase + 16] = acc[mt][1][r];
    }
  }
}

// TM=16 paths: lane holds all D consecutive cols (i == mt) for its (n, z).
template<int D, int MTILES>
__device__ __forceinline__ void store_dense(float* __restrict__ ob, int z0,
                                            int lane, int nbase,
                                            f32x4 (&acc)[MTILES][2])
{
  const int rbase = ((lane >> 4) & 3) << 2;
  #pragma unroll
  for (int nt = 0; nt < 2; ++nt) {
    const int colb = (nbase + nt * 16) * D;
    #pragma unroll
    for (int r = 0; r < 4; ++r) {
      int z = z0 + rbase + r;
      float* p = ob + (size_t)z * ROWLEN + colb;
      if (D == 5) {
        f32x4u v4 = { acc[0][nt][r], acc[1][nt][r], acc[2][nt][r], acc[3][nt][r] };
        *(f32x4u*)p = v4;
        p[4] = acc[4][nt][r];
      } else {  // D == 3
        f32x2u v2 = { acc[0][nt][r], acc[1][nt][r] };
        *(f32x2u*)p = v2;
        p[2] = acc[2][nt][r];
      }
    }
  }
}

// ---- persistent per-irrep path ------------------------------------------
template<int D, int TM, bool GUARD, int NWGS>
__device__ __forceinline__ void linpath(const float* __restrict__ xb,
                                        const float* __restrict__ wb,
                                        float* __restrict__ ob,
                                        int wgid, char* lds)
{
  constexpr int MT     = TM * D;
  constexpr int MTILES = MT / 16;
  constexpr int PT     = TM / 8;
  constexpr int NTILES = (NROWS + TM - 1) / TM;
  constexpr int BUFB   = MT * 256;
  constexpr float ALPHA = 0.088388347648318447f;  // 128^-0.5

  const int tid   = threadIdx.x;
  const int lane  = tid & 63;
  const int wv    = tid >> 6;
  const int l15   = lane & 15;
  const int kr    = ((lane >> 4) & 3) << 3;
  const int nbase = (wv << 5) + l15;

  // weights -> registers once per WG (K=128 x N=32 per wave), ALPHA folded
  bf16x8 bfr[2][4];
  #pragma unroll
  for (int nt = 0; nt < 2; ++nt)
    #pragma unroll
    for (int ks = 0; ks < 4; ++ks)
      #pragma unroll
      for (int j = 0; j < 8; ++j)
        bfr[nt][ks][j] =
            (short)f2b(wb[(ks * 32 + kr + j) * 128 + nbase + nt * 16] * ALPHA);

  char* buf0 = lds;
  char* buf1 = lds + BUFB;

  // prologue: stage first tile
  int t0 = wgid;
  {
    f32x4 vf[PT][D];
    if (GUARD && t0 == NTILES - 1) load_tile<D, TM, true>(xb, t0, tid, vf);
    else                           load_tile<D, TM, false>(xb, t0, tid, vf);
    write_tile<D, TM>(buf0, tid, vf);
  }
  __syncthreads();

  int cur = 0;
  for (int t = t0; t < NTILES; t += NWGS) {
    char* bc = cur ? buf1 : buf0;
    char* bn = cur ? buf0 : buf1;
    const int tn = t + NWGS;
    const bool have = tn < NTILES;

    // 1. issue next tile's global loads into regs (latency hides under MFMA)
    f32x4 vf[PT][D];
    if (have) {
      if (GUARD && tn == NTILES - 1) load_tile<D, TM, true>(xb, tn, tid, vf);
      else                           load_tile<D, TM, false>(xb, tn, tid, vf);
    }

    // 2. MFMA on current buffer
    f32x4 acc[MTILES][2];
    #pragma unroll
    for (int mt = 0; mt < MTILES; ++mt) {
      acc[mt][0] = f32x4{0.f, 0.f, 0.f, 0.f};
      acc[mt][1] = f32x4{0.f, 0.f, 0.f, 0.f};
    }
    #pragma unroll
    for (int ks = 0; ks < 4; ++ks) {
      const int chunkbase = ks * 4 + ((lane >> 4) & 3);  // (ks*32+kr)>>3
      #pragma unroll
      for (int mt = 0; mt < MTILES; ++mt) {
        int m = (mt << 4) + l15;
        int byte = m * 256 + ((chunkbase ^ (m & 7)) << 4);
        bf16x8 a = *(const bf16x8*)(bc + byte);
        acc[mt][0] = __builtin_amdgcn_mfma_f32_16x16x32_bf16(a, bfr[0][ks], acc[mt][0], 0, 0, 0);
        acc[mt][1] = __builtin_amdgcn_mfma_f32_16x16x32_bf16(a, bfr[1][ks], acc[mt][1], 0, 0, 0);
      }
    }

    // 3. convert + LDS-write next tile (global loads have landed by now)
    if (have) write_tile<D, TM>(bn, tid, vf);

    // 4. store current tile's output (dense per-lane spans)
    if (D == 1) {
      if (GUARD && t == NTILES - 1)
        store_d1<true, TM, MTILES>(ob, t * TM, lane, nbase, acc);
      else
        store_d1<false, TM, MTILES>(ob, t * TM, lane, nbase, acc);
    } else {
      store_dense<D, MTILES>(ob, t * TM, lane, nbase, acc);
    }

    __syncthreads();
    cur ^= 1;
  }
}

// WG split proportional to bytes (1:3:5), grid = 1024 = 4 WGs/CU.
constexpr int NW1 = 114;   // D=1, TM=64, 1563 tiles
constexpr int NW3 = 341;   // D=3, TM=16, 6250 tiles
constexpr int NW5 = 569;   // D=5, TM=16, 6250 tiles

__global__ __launch_bounds__(256, 4)
void linear_irreps_kernel(const float* __restrict__ x, const float* __restrict__ w,
                          float* __restrict__ out)
{
  extern __shared__ __align__(16) char lds[];
  int wg = blockIdx.x;
  if (wg < NW1) {
    linpath<1, 64, true,  NW1>(x,       w,         out,       wg,             lds);
  } else if (wg < NW1 + NW3) {
    linpath<3, 16, false, NW3>(x + 128, w + 16384, out + 128, wg - NW1,       lds);
  } else {
    linpath<5, 16, false, NW5>(x + 512, w + 32768, out + 512, wg - NW1 - NW3, lds);
  }
}

extern "C" void kernel_launch(void* const* d_in, const int* in_sizes, int n_in,
                              void* d_out, int out_size, void* d_ws, size_t ws_size,
                              hipStream_t stream) {
  const float* x = (const float*)d_in[0];
  const float* w = (const float*)d_in[1];
  float* out = (float*)d_out;
  (void)in_sizes; (void)n_in; (void)out_size; (void)d_ws; (void)ws_size;
  dim3 grid(NW1 + NW3 + NW5);
  dim3 block(256);
  hipLaunchKernelGGL(linear_irreps_kernel, grid, block, 40960, stream, x, w, out);
}